// Round 5
// baseline (405.008 us; speedup 1.0000x reference)
//
#include <hip/hip_runtime.h>
#include <cmath>

#define NLEVELS 16
#define TBL     (1u << 19)
#define HMASK   0x7FFFFu
#define NPTS    524288

typedef float v4f __attribute__((ext_vector_type(4)));

struct LevelParams {
    float cell[NLEVELS];   // fp32 value of 1.0f / (float)RES[l], matching numpy
};

// ---------------------------------------------------------------------------
// EXACT replication of the numpy fp32 chain: hashes + trilinear weights.
// Split so callers can issue all gathers before computing weights.
// ---------------------------------------------------------------------------
__device__ __forceinline__ void ngp_hash(
    float x, float y, float z, float cell, unsigned* __restrict__ h,
    float& dx, float& dy, float& dz)
{
    const float ux = x / cell;
    const float uy = y / cell;
    const float uz = z / cell;
    const float fx = floorf(ux);
    const float fy = floorf(uy);
    const float fz = floorf(uz);
    dx = ux - fx;
    dy = uy - fy;
    dz = uz - fz;

    const unsigned ix = (unsigned)(int)fx;
    const unsigned iy = (unsigned)(int)fy;
    const unsigned iz = (unsigned)(int)fz;

    const unsigned hx0 = ix;
    const unsigned hx1 = ix + 1u;
    const unsigned hy0 = iy * 2654435761u;
    const unsigned hy1 = (iy + 1u) * 2654435761u;
    const unsigned hz0 = iz * 805459861u;
    const unsigned hz1 = (iz + 1u) * 805459861u;

    h[0] = (hx0 ^ hy0 ^ hz0) & HMASK;
    h[1] = (hx0 ^ hy0 ^ hz1) & HMASK;
    h[2] = (hx0 ^ hy1 ^ hz0) & HMASK;
    h[3] = (hx0 ^ hy1 ^ hz1) & HMASK;
    h[4] = (hx1 ^ hy0 ^ hz0) & HMASK;
    h[5] = (hx1 ^ hy0 ^ hz1) & HMASK;
    h[6] = (hx1 ^ hy1 ^ hz0) & HMASK;
    h[7] = (hx1 ^ hy1 ^ hz1) & HMASK;
}

__device__ __forceinline__ void ngp_weights(
    float dx, float dy, float dz, float* __restrict__ w)
{
    const float wx0 = 1.0f - dx;
    const float wy0 = 1.0f - dy;
    const float wz0 = 1.0f - dz;
    const float p00 = wx0 * wy0;
    const float p01 = wx0 * dy;
    const float p10 = dx * wy0;
    const float p11 = dx * dy;
    w[0] = p00 * wz0;
    w[1] = p00 * dz;
    w[2] = p01 * wz0;
    w[3] = p01 * dz;
    w[4] = p10 * wz0;
    w[5] = p10 * dz;
    w[6] = p11 * wz0;
    w[7] = p11 * dz;
}

__device__ __forceinline__ float2 ngp_combine(
    const float* __restrict__ w, const float2* __restrict__ e)
{
    float c0 = w[0] * e[0].x;
    float c1 = w[0] * e[0].y;
    #pragma unroll
    for (int c = 1; c < 8; ++c) {
        c0 += w[c] * e[c].x;
        c1 += w[c] * e[c].y;
    }
    return make_float2(c0, c1);
}

// ---------------------------------------------------------------------------
// Phase 1: one block = 512 points x ONE level, 2 points per thread for MLP
// (16 outstanding gathers/thread). blockIdx encoding pins level%8 to XCD
// (round-robin dispatch: XCD = b % 8) and splits levels {0-7}/{8-15} into two
// temporal phases so each XCD's 4 MB L2 holds one 4 MB table at a time.
//   b = phase*8192 + chunk*8 + (level%8),  chunk in [0,1024)
// ---------------------------------------------------------------------------
__global__ __launch_bounds__(256) void ngp_phase1(
    const float* __restrict__ xyz,
    const float* __restrict__ tables,
    float2* __restrict__ ws,          // [L][N] float2
    LevelParams lp)
{
    const unsigned b = blockIdx.x;
    const int level = (int)(((b >> 13) << 3) | (b & 7u));
    const int chunk = (int)((b >> 3) & 1023u);
    const int n0 = chunk * 512 + threadIdx.x;
    const int n1 = n0 + 256;

    const float x0 = xyz[3 * n0 + 0];
    const float y0 = xyz[3 * n0 + 1];
    const float z0 = xyz[3 * n0 + 2];
    const float x1 = xyz[3 * n1 + 0];
    const float y1 = xyz[3 * n1 + 1];
    const float z1 = xyz[3 * n1 + 2];

    const float cell = lp.cell[level];
    const float2* __restrict__ tab = (const float2*)tables + ((size_t)level << 19);

    unsigned h0[8], h1[8];
    float dx0, dy0, dz0, dx1, dy1, dz1;
    ngp_hash(x0, y0, z0, cell, h0, dx0, dy0, dz0);
    ngp_hash(x1, y1, z1, cell, h1, dx1, dy1, dz1);

    // issue all 16 gathers back-to-back before any use
    float2 e0[8], e1[8];
    #pragma unroll
    for (int c = 0; c < 8; ++c) e0[c] = tab[h0[c]];
    #pragma unroll
    for (int c = 0; c < 8; ++c) e1[c] = tab[h1[c]];

    // weights computed in the load shadow
    float w0[8], w1[8];
    ngp_weights(dx0, dy0, dz0, w0);
    ngp_weights(dx1, dy1, dz1, w1);

    const float2 r0 = ngp_combine(w0, e0);
    const float2 r1 = ngp_combine(w1, e1);

    // [l][n] layout: 512B contiguous per wave per store
    ws[(size_t)level * NPTS + n0] = r0;
    ws[(size_t)level * NPTS + n1] = r1;
}

// ---------------------------------------------------------------------------
// Phase 2: transpose ws[l][n][2] -> out[n][32] via LDS.
// Loads: 16 per thread, each wave-coalesced 512 B. Stores: contiguous float4.
// LDS row stride 258 float2 -> bank = (8k+2m)%32, worst 2-way (free).
// ---------------------------------------------------------------------------
#define P2STRIDE 258

__global__ __launch_bounds__(256) void ngp_phase2(
    const float2* __restrict__ ws,
    float* __restrict__ out)
{
    __shared__ float2 lds[NLEVELS * P2STRIDE];
    const unsigned base = blockIdx.x * 256;
    const unsigned tid = threadIdx.x;

    #pragma unroll
    for (int l = 0; l < NLEVELS; ++l)
        lds[l * P2STRIDE + tid] = ws[(size_t)l * NPTS + base + tid];

    __syncthreads();

    #pragma unroll
    for (int it = 0; it < 8; ++it) {
        const unsigned j = it * 256 + tid;       // block-local float4 index
        const unsigned nl = j >> 3;              // local point
        const unsigned k = j & 7u;               // level pair
        const float2 a = lds[(2u * k)      * P2STRIDE + nl];
        const float2 b = lds[(2u * k + 1u) * P2STRIDE + nl];
        v4f v = { a.x, a.y, b.x, b.y };
        *(v4f*)(out + (size_t)base * 32 + (size_t)j * 4) = v;
    }
}

// ---------------------------------------------------------------------------
// Fallback single-kernel (used only if ws_size is too small).
// ---------------------------------------------------------------------------
__global__ __launch_bounds__(256) void ngp_encode(
    const float* __restrict__ xyz,
    const float* __restrict__ tables,
    float* __restrict__ out,
    LevelParams lp)
{
    const int n = blockIdx.x * 256 + threadIdx.x;
    const float x = xyz[3 * n + 0];
    const float y = xyz[3 * n + 1];
    const float z = xyz[3 * n + 2];

    float acc[2 * NLEVELS];
    const float2* __restrict__ tab_base = (const float2*)tables;

    #pragma unroll
    for (int l = 0; l < NLEVELS; ++l) {
        unsigned h[8];
        float dx, dy, dz;
        ngp_hash(x, y, z, lp.cell[l], h, dx, dy, dz);
        const float2* __restrict__ tab = tab_base + ((size_t)l << 19);
        float2 e[8];
        #pragma unroll
        for (int c = 0; c < 8; ++c) e[c] = tab[h[c]];
        float w[8];
        ngp_weights(dx, dy, dz, w);
        const float2 r = ngp_combine(w, e);
        acc[2 * l + 0] = r.x;
        acc[2 * l + 1] = r.y;
    }

    v4f* o4 = (v4f*)(out + (size_t)n * 32);
    #pragma unroll
    for (int j = 0; j < 8; ++j) {
        v4f v = { acc[4 * j + 0], acc[4 * j + 1],
                  acc[4 * j + 2], acc[4 * j + 3] };
        o4[j] = v;
    }
}

extern "C" void kernel_launch(void* const* d_in, const int* in_sizes, int n_in,
                              void* d_out, int out_size, void* d_ws, size_t ws_size,
                              hipStream_t stream) {
    const float* xyz    = (const float*)d_in[0];
    const float* tables = (const float*)d_in[1];
    float* out          = (float*)d_out;

    // Compute RES exactly as CPython does (glibc double exp/log/pow), then
    // cell = 1/RES in fp32 exactly as numpy float32 division.
    LevelParams lp;
    const double B = std::exp((std::log(2048.0) - std::log(16.0)) / 15.0);
    for (int i = 0; i < NLEVELS; ++i) {
        const double r = std::floor(16.0 * std::pow(B, (double)i));
        lp.cell[i] = 1.0f / (float)r;
    }

    const size_t ws_needed = (size_t)NLEVELS * NPTS * sizeof(float2); // 64 MB

    if (ws_size >= ws_needed) {
        float2* ws = (float2*)d_ws;
        // 16 levels x 1024 chunks of 512 points
        hipLaunchKernelGGL(ngp_phase1, dim3(NLEVELS * (NPTS / 512)), dim3(256), 0, stream,
                           xyz, tables, ws, lp);
        hipLaunchKernelGGL(ngp_phase2, dim3(NPTS / 256), dim3(256), 0, stream,
                           ws, out);
    } else {
        hipLaunchKernelGGL(ngp_encode, dim3(NPTS / 256), dim3(256), 0, stream,
                           xyz, tables, out, lp);
    }
}

// Round 6
// 377.858 us; speedup vs baseline: 1.0719x; 1.0719x over previous
//
#include <hip/hip_runtime.h>
#include <cmath>

#define NLEVELS 16
#define HMASK   0x7FFFFu
#define NPTS    524288
#define NBUCKET 32768          // 32^3 Morton buckets

typedef float v4f __attribute__((ext_vector_type(4)));

struct LevelParams {
    float cell[NLEVELS];       // fp32 value of 1.0f / (float)RES[l], matching numpy
};

// ---------------------------------------------------------------------------
// Morton bucketing (5 bits/axis)
// ---------------------------------------------------------------------------
__device__ __forceinline__ unsigned spread5(unsigned v) {
    return (v & 1u) | ((v & 2u) << 2) | ((v & 4u) << 4) |
           ((v & 8u) << 6) | ((v & 16u) << 8);
}

__device__ __forceinline__ unsigned morton_key(float x, float y, float z) {
    unsigned bx = min(31u, (unsigned)(x * 32.0f));
    unsigned by = min(31u, (unsigned)(y * 32.0f));
    unsigned bz = min(31u, (unsigned)(z * 32.0f));
    return spread5(bx) | (spread5(by) << 1) | (spread5(bz) << 2);
}

// ---------------------------------------------------------------------------
// EXACT replication of the numpy fp32 chain: hashes + trilinear weights.
// ---------------------------------------------------------------------------
__device__ __forceinline__ void ngp_hash(
    float x, float y, float z, float cell, unsigned* __restrict__ h,
    float& dx, float& dy, float& dz)
{
    const float ux = x / cell;
    const float uy = y / cell;
    const float uz = z / cell;
    const float fx = floorf(ux);
    const float fy = floorf(uy);
    const float fz = floorf(uz);
    dx = ux - fx;
    dy = uy - fy;
    dz = uz - fz;

    const unsigned ix = (unsigned)(int)fx;
    const unsigned iy = (unsigned)(int)fy;
    const unsigned iz = (unsigned)(int)fz;

    const unsigned hx0 = ix;
    const unsigned hx1 = ix + 1u;
    const unsigned hy0 = iy * 2654435761u;
    const unsigned hy1 = (iy + 1u) * 2654435761u;
    const unsigned hz0 = iz * 805459861u;
    const unsigned hz1 = (iz + 1u) * 805459861u;

    h[0] = (hx0 ^ hy0 ^ hz0) & HMASK;
    h[1] = (hx0 ^ hy0 ^ hz1) & HMASK;
    h[2] = (hx0 ^ hy1 ^ hz0) & HMASK;
    h[3] = (hx0 ^ hy1 ^ hz1) & HMASK;
    h[4] = (hx1 ^ hy0 ^ hz0) & HMASK;
    h[5] = (hx1 ^ hy0 ^ hz1) & HMASK;
    h[6] = (hx1 ^ hy1 ^ hz0) & HMASK;
    h[7] = (hx1 ^ hy1 ^ hz1) & HMASK;
}

__device__ __forceinline__ void ngp_weights(
    float dx, float dy, float dz, float* __restrict__ w)
{
    const float wx0 = 1.0f - dx;
    const float wy0 = 1.0f - dy;
    const float wz0 = 1.0f - dz;
    const float p00 = wx0 * wy0;
    const float p01 = wx0 * dy;
    const float p10 = dx * wy0;
    const float p11 = dx * dy;
    w[0] = p00 * wz0;
    w[1] = p00 * dz;
    w[2] = p01 * wz0;
    w[3] = p01 * dz;
    w[4] = p10 * wz0;
    w[5] = p10 * dz;
    w[6] = p11 * wz0;
    w[7] = p11 * dz;
}

__device__ __forceinline__ float2 ngp_combine(
    const float* __restrict__ w, const float2* __restrict__ e)
{
    float c0 = w[0] * e[0].x;
    float c1 = w[0] * e[0].y;
    #pragma unroll
    for (int c = 1; c < 8; ++c) {
        c0 += w[c] * e[c].x;
        c1 += w[c] * e[c].y;
    }
    return make_float2(c0, c1);
}

// ---------------------------------------------------------------------------
// Sort kernel A: histogram of Morton buckets.
// ---------------------------------------------------------------------------
__global__ __launch_bounds__(256) void bucket_count(
    const float* __restrict__ xyz, unsigned* __restrict__ counts)
{
    const int n = blockIdx.x * 256 + threadIdx.x;
    const float x = xyz[3 * n + 0];
    const float y = xyz[3 * n + 1];
    const float z = xyz[3 * n + 2];
    atomicAdd(&counts[morton_key(x, y, z)], 1u);
}

// ---------------------------------------------------------------------------
// Sort kernel B: exclusive prefix sum of 32768 counts -> cursor[].
// One block of 1024 threads, 32 buckets per thread, two passes over counts.
// ---------------------------------------------------------------------------
__global__ __launch_bounds__(1024) void bucket_scan(
    const unsigned* __restrict__ counts, unsigned* __restrict__ cursor)
{
    __shared__ unsigned psum[1024];
    const unsigned t = threadIdx.x;

    unsigned s = 0;
    for (int i = 0; i < 32; ++i) s += counts[t * 32 + i];
    psum[t] = s;
    __syncthreads();

    // inclusive block scan
    for (unsigned off = 1; off < 1024; off <<= 1) {
        unsigned v = 0;
        if (t >= off) v = psum[t - off];
        __syncthreads();
        if (t >= off) psum[t] += v;
        __syncthreads();
    }

    unsigned excl = psum[t] - s;   // exclusive prefix of this thread's segment
    for (int i = 0; i < 32; ++i) {
        cursor[t * 32 + i] = excl;
        excl += counts[t * 32 + i];
    }
}

// ---------------------------------------------------------------------------
// Sort kernel C: scatter points into sorted order.
// ---------------------------------------------------------------------------
__global__ __launch_bounds__(256) void bucket_scatter(
    const float* __restrict__ xyz, unsigned* __restrict__ cursor,
    unsigned* __restrict__ perm, float* __restrict__ xyz_sorted)
{
    const int n = blockIdx.x * 256 + threadIdx.x;
    const float x = xyz[3 * n + 0];
    const float y = xyz[3 * n + 1];
    const float z = xyz[3 * n + 2];
    const unsigned key = morton_key(x, y, z);
    const unsigned p = atomicAdd(&cursor[key], 1u);
    perm[p] = (unsigned)n;
    xyz_sorted[3 * p + 0] = x;
    xyz_sorted[3 * p + 1] = y;
    xyz_sorted[3 * p + 2] = z;
}

// ---------------------------------------------------------------------------
// Phase 1: one block = 256 sorted points x ONE level (round-4 structure).
// blockIdx encoding pins level%8 to XCD (round-robin dispatch: XCD = b % 8)
// and splits levels {0-7}/{8-15} into two temporal phases so each XCD's
// 4 MB L2 holds one 4 MB table at a time.
//   b = phase*16384 + chunk*8 + (level%8)
// Sorted point order makes waves spatially compact: coarse levels coalesce
// same-line lanes in the TA; mid levels become L1-resident.
// ---------------------------------------------------------------------------
__global__ __launch_bounds__(256) void ngp_phase1(
    const float* __restrict__ xyz_sorted,
    const float* __restrict__ tables,
    float2* __restrict__ ws,          // [L][N] float2, sorted point order
    LevelParams lp)
{
    const unsigned b = blockIdx.x;
    const int level = (int)(((b >> 14) << 3) | (b & 7u));
    const int chunk = (int)((b >> 3) & 2047u);
    const int p = chunk * 256 + threadIdx.x;

    const float x = xyz_sorted[3 * p + 0];
    const float y = xyz_sorted[3 * p + 1];
    const float z = xyz_sorted[3 * p + 2];

    const float cell = lp.cell[level];
    const float2* __restrict__ tab = (const float2*)tables + ((size_t)level << 19);

    unsigned h[8];
    float dx, dy, dz;
    ngp_hash(x, y, z, cell, h, dx, dy, dz);

    float2 e[8];
    #pragma unroll
    for (int c = 0; c < 8; ++c) e[c] = tab[h[c]];

    float w[8];
    ngp_weights(dx, dy, dz, w);

    const float2 r = ngp_combine(w, e);

    ws[(size_t)level * NPTS + p] = r;
}

// ---------------------------------------------------------------------------
// Phase 2: un-permute + transpose ws[l][p] -> out[perm[p]][32] via LDS.
// Loads fully coalesced; stores are full 64B lines scattered by perm (the
// 8 lanes of one point write 128B contiguous; TA merges into 2 line writes).
// LDS stride 257 float2: banks (4k+2pl)%32 -> worst 2-way (free).
// ---------------------------------------------------------------------------
#define P2S 257

__global__ __launch_bounds__(256) void ngp_phase2(
    const float2* __restrict__ ws,
    const unsigned* __restrict__ perm,
    float* __restrict__ out)
{
    __shared__ float2 lds[NLEVELS * P2S];
    __shared__ unsigned nperm[256];
    const unsigned base = blockIdx.x * 256;
    const unsigned t = threadIdx.x;

    nperm[t] = perm[base + t];
    #pragma unroll
    for (int l = 0; l < NLEVELS; ++l)
        lds[l * P2S + t] = ws[(size_t)l * NPTS + base + t];

    __syncthreads();

    #pragma unroll
    for (int it = 0; it < 8; ++it) {
        const unsigned j = it * 256 + t;
        const unsigned pl = j >> 3;          // local sorted point
        const unsigned k = j & 7u;           // level pair
        const float2 a = lds[(2u * k)      * P2S + pl];
        const float2 b = lds[(2u * k + 1u) * P2S + pl];
        v4f v = { a.x, a.y, b.x, b.y };
        *(v4f*)(out + (size_t)nperm[pl] * 32 + k * 4) = v;
    }
}

// ---------------------------------------------------------------------------
// Fallback single-kernel (used only if ws_size is too small).
// ---------------------------------------------------------------------------
__global__ __launch_bounds__(256) void ngp_encode(
    const float* __restrict__ xyz,
    const float* __restrict__ tables,
    float* __restrict__ out,
    LevelParams lp)
{
    const int n = blockIdx.x * 256 + threadIdx.x;
    const float x = xyz[3 * n + 0];
    const float y = xyz[3 * n + 1];
    const float z = xyz[3 * n + 2];

    float acc[2 * NLEVELS];
    const float2* __restrict__ tab_base = (const float2*)tables;

    #pragma unroll
    for (int l = 0; l < NLEVELS; ++l) {
        unsigned h[8];
        float dx, dy, dz;
        ngp_hash(x, y, z, lp.cell[l], h, dx, dy, dz);
        const float2* __restrict__ tab = tab_base + ((size_t)l << 19);
        float2 e[8];
        #pragma unroll
        for (int c = 0; c < 8; ++c) e[c] = tab[h[c]];
        float w[8];
        ngp_weights(dx, dy, dz, w);
        const float2 r = ngp_combine(w, e);
        acc[2 * l + 0] = r.x;
        acc[2 * l + 1] = r.y;
    }

    v4f* o4 = (v4f*)(out + (size_t)n * 32);
    #pragma unroll
    for (int j = 0; j < 8; ++j) {
        v4f v = { acc[4 * j + 0], acc[4 * j + 1],
                  acc[4 * j + 2], acc[4 * j + 3] };
        o4[j] = v;
    }
}

extern "C" void kernel_launch(void* const* d_in, const int* in_sizes, int n_in,
                              void* d_out, int out_size, void* d_ws, size_t ws_size,
                              hipStream_t stream) {
    const float* xyz    = (const float*)d_in[0];
    const float* tables = (const float*)d_in[1];
    float* out          = (float*)d_out;

    // Compute RES exactly as CPython does (glibc double exp/log/pow), then
    // cell = 1/RES in fp32 exactly as numpy float32 division.
    LevelParams lp;
    const double B = std::exp((std::log(2048.0) - std::log(16.0)) / 15.0);
    for (int i = 0; i < NLEVELS; ++i) {
        const double r = std::floor(16.0 * std::pow(B, (double)i));
        lp.cell[i] = 1.0f / (float)r;
    }

    // Workspace layout (16B-aligned blocks):
    //   [0, 64MB)        float2 ws_feat[L][N]
    //   [64MB, +6MB)     float  xyz_sorted[N*3]
    //   [+2MB)           u32    perm[N]
    //   [+128KB)         u32    counts[NBUCKET]
    //   [+128KB)         u32    cursor[NBUCKET]
    const size_t off_feat   = 0;
    const size_t off_xyzs   = off_feat + (size_t)NLEVELS * NPTS * sizeof(float2);
    const size_t off_perm   = off_xyzs + (size_t)NPTS * 3 * sizeof(float);
    const size_t off_counts = off_perm + (size_t)NPTS * sizeof(unsigned);
    const size_t off_cursor = off_counts + (size_t)NBUCKET * sizeof(unsigned);
    const size_t ws_needed  = off_cursor + (size_t)NBUCKET * sizeof(unsigned);

    if (ws_size >= ws_needed) {
        char* wsb = (char*)d_ws;
        float2*   ws_feat    = (float2*)(wsb + off_feat);
        float*    xyz_sorted = (float*)(wsb + off_xyzs);
        unsigned* perm       = (unsigned*)(wsb + off_perm);
        unsigned* counts     = (unsigned*)(wsb + off_counts);
        unsigned* cursor     = (unsigned*)(wsb + off_cursor);

        hipMemsetAsync(counts, 0, NBUCKET * sizeof(unsigned), stream);
        hipLaunchKernelGGL(bucket_count, dim3(NPTS / 256), dim3(256), 0, stream,
                           xyz, counts);
        hipLaunchKernelGGL(bucket_scan, dim3(1), dim3(1024), 0, stream,
                           counts, cursor);
        hipLaunchKernelGGL(bucket_scatter, dim3(NPTS / 256), dim3(256), 0, stream,
                           xyz, cursor, perm, xyz_sorted);
        hipLaunchKernelGGL(ngp_phase1, dim3(NLEVELS * (NPTS / 256)), dim3(256), 0, stream,
                           xyz_sorted, tables, ws_feat, lp);
        hipLaunchKernelGGL(ngp_phase2, dim3(NPTS / 256), dim3(256), 0, stream,
                           ws_feat, perm, out);
    } else {
        hipLaunchKernelGGL(ngp_encode, dim3(NPTS / 256), dim3(256), 0, stream,
                           xyz, tables, out, lp);
    }
}

// Round 7
// 356.636 us; speedup vs baseline: 1.1356x; 1.0595x over previous
//
#include <hip/hip_runtime.h>
#include <cmath>

#define NLEVELS 16
#define HMASK   0x7FFFFu
#define NPTS    524288
#define NBUCKET 32768          // 32^3 Morton buckets

typedef float v4f __attribute__((ext_vector_type(4)));

struct LevelParams {
    float cell[NLEVELS];       // fp32 value of 1.0f / (float)RES[l], matching numpy
};

// ---------------------------------------------------------------------------
// Morton bucketing (5 bits/axis)
// ---------------------------------------------------------------------------
__device__ __forceinline__ unsigned spread5(unsigned v) {
    return (v & 1u) | ((v & 2u) << 2) | ((v & 4u) << 4) |
           ((v & 8u) << 6) | ((v & 16u) << 8);
}

__device__ __forceinline__ unsigned morton_key(float x, float y, float z) {
    unsigned bx = min(31u, (unsigned)(x * 32.0f));
    unsigned by = min(31u, (unsigned)(y * 32.0f));
    unsigned bz = min(31u, (unsigned)(z * 32.0f));
    return spread5(bx) | (spread5(by) << 1) | (spread5(bz) << 2);
}

// ---------------------------------------------------------------------------
// EXACT replication of the numpy fp32 chain: hashes + trilinear weights.
// ---------------------------------------------------------------------------
__device__ __forceinline__ void ngp_hash(
    float x, float y, float z, float cell, unsigned* __restrict__ h,
    float& dx, float& dy, float& dz)
{
    const float ux = x / cell;
    const float uy = y / cell;
    const float uz = z / cell;
    const float fx = floorf(ux);
    const float fy = floorf(uy);
    const float fz = floorf(uz);
    dx = ux - fx;
    dy = uy - fy;
    dz = uz - fz;

    const unsigned ix = (unsigned)(int)fx;
    const unsigned iy = (unsigned)(int)fy;
    const unsigned iz = (unsigned)(int)fz;

    const unsigned hx0 = ix;
    const unsigned hx1 = ix + 1u;
    const unsigned hy0 = iy * 2654435761u;
    const unsigned hy1 = (iy + 1u) * 2654435761u;
    const unsigned hz0 = iz * 805459861u;
    const unsigned hz1 = (iz + 1u) * 805459861u;

    h[0] = (hx0 ^ hy0 ^ hz0) & HMASK;
    h[1] = (hx0 ^ hy0 ^ hz1) & HMASK;
    h[2] = (hx0 ^ hy1 ^ hz0) & HMASK;
    h[3] = (hx0 ^ hy1 ^ hz1) & HMASK;
    h[4] = (hx1 ^ hy0 ^ hz0) & HMASK;
    h[5] = (hx1 ^ hy0 ^ hz1) & HMASK;
    h[6] = (hx1 ^ hy1 ^ hz0) & HMASK;
    h[7] = (hx1 ^ hy1 ^ hz1) & HMASK;
}

__device__ __forceinline__ void ngp_weights(
    float dx, float dy, float dz, float* __restrict__ w)
{
    const float wx0 = 1.0f - dx;
    const float wy0 = 1.0f - dy;
    const float wz0 = 1.0f - dz;
    const float p00 = wx0 * wy0;
    const float p01 = wx0 * dy;
    const float p10 = dx * wy0;
    const float p11 = dx * dy;
    w[0] = p00 * wz0;
    w[1] = p00 * dz;
    w[2] = p01 * wz0;
    w[3] = p01 * dz;
    w[4] = p10 * wz0;
    w[5] = p10 * dz;
    w[6] = p11 * wz0;
    w[7] = p11 * dz;
}

__device__ __forceinline__ float2 ngp_combine(
    const float* __restrict__ w, const float2* __restrict__ e)
{
    float c0 = w[0] * e[0].x;
    float c1 = w[0] * e[0].y;
    #pragma unroll
    for (int c = 1; c < 8; ++c) {
        c0 += w[c] * e[c].x;
        c1 += w[c] * e[c].y;
    }
    return make_float2(c0, c1);
}

// ---------------------------------------------------------------------------
// Sort kernel A: histogram of Morton buckets.
// ---------------------------------------------------------------------------
__global__ __launch_bounds__(256) void bucket_count(
    const float* __restrict__ xyz, unsigned* __restrict__ counts)
{
    const int n = blockIdx.x * 256 + threadIdx.x;
    const float x = xyz[3 * n + 0];
    const float y = xyz[3 * n + 1];
    const float z = xyz[3 * n + 2];
    atomicAdd(&counts[morton_key(x, y, z)], 1u);
}

// ---------------------------------------------------------------------------
// Sort kernel B: exclusive prefix sum of 32768 counts -> cursor[].
// One block of 1024 threads, 32 buckets per thread, two passes over counts.
// ---------------------------------------------------------------------------
__global__ __launch_bounds__(1024) void bucket_scan(
    const unsigned* __restrict__ counts, unsigned* __restrict__ cursor)
{
    __shared__ unsigned psum[1024];
    const unsigned t = threadIdx.x;

    unsigned s = 0;
    for (int i = 0; i < 32; ++i) s += counts[t * 32 + i];
    psum[t] = s;
    __syncthreads();

    // inclusive block scan
    for (unsigned off = 1; off < 1024; off <<= 1) {
        unsigned v = 0;
        if (t >= off) v = psum[t - off];
        __syncthreads();
        if (t >= off) psum[t] += v;
        __syncthreads();
    }

    unsigned excl = psum[t] - s;   // exclusive prefix of this thread's segment
    for (int i = 0; i < 32; ++i) {
        cursor[t * 32 + i] = excl;
        excl += counts[t * 32 + i];
    }
}

// ---------------------------------------------------------------------------
// Sort kernel C: scatter points into sorted order.
// ---------------------------------------------------------------------------
__global__ __launch_bounds__(256) void bucket_scatter(
    const float* __restrict__ xyz, unsigned* __restrict__ cursor,
    unsigned* __restrict__ perm, float* __restrict__ xyz_sorted)
{
    const int n = blockIdx.x * 256 + threadIdx.x;
    const float x = xyz[3 * n + 0];
    const float y = xyz[3 * n + 1];
    const float z = xyz[3 * n + 2];
    const unsigned key = morton_key(x, y, z);
    const unsigned p = atomicAdd(&cursor[key], 1u);
    perm[p] = (unsigned)n;
    xyz_sorted[3 * p + 0] = x;
    xyz_sorted[3 * p + 1] = y;
    xyz_sorted[3 * p + 2] = z;
}

// ---------------------------------------------------------------------------
// Phase 1: one block = 256 sorted points x ONE level.
// LEVEL-MAJOR dispatch (b = level*2048 + chunk): all 8 XCDs work on the same
// level concurrently, each caching its own copy of the current 4 MB table in
// its L2 (fills come from L3, so HBM still sees each table once). This
// balances L2 tag-port load perfectly across XCDs — the previous level->XCD
// pinning gave the worst XCD 2x the requests (lvl7+lvl15) and bound the
// kernel at 207 us.
// ---------------------------------------------------------------------------
__global__ __launch_bounds__(256) void ngp_phase1(
    const float* __restrict__ xyz_sorted,
    const float* __restrict__ tables,
    float2* __restrict__ ws,          // [L][N] float2, sorted point order
    LevelParams lp)
{
    const unsigned b = blockIdx.x;
    const int level = (int)(b >> 11);
    const int chunk = (int)(b & 2047u);
    const int p = chunk * 256 + threadIdx.x;

    const float x = xyz_sorted[3 * p + 0];
    const float y = xyz_sorted[3 * p + 1];
    const float z = xyz_sorted[3 * p + 2];

    const float cell = lp.cell[level];
    const float2* __restrict__ tab = (const float2*)tables + ((size_t)level << 19);

    unsigned h[8];
    float dx, dy, dz;
    ngp_hash(x, y, z, cell, h, dx, dy, dz);

    float2 e[8];
    #pragma unroll
    for (int c = 0; c < 8; ++c) e[c] = tab[h[c]];

    float w[8];
    ngp_weights(dx, dy, dz, w);

    const float2 r = ngp_combine(w, e);

    ws[(size_t)level * NPTS + p] = r;
}

// ---------------------------------------------------------------------------
// Phase 2: un-permute + transpose ws[l][p] -> out[perm[p]][32] via LDS.
// Loads fully coalesced; stores are full 64B lines scattered by perm (the
// 8 lanes of one point write 128B contiguous; TA merges into 2 line writes).
// LDS stride 257 float2: banks (4k+2pl)%32 -> worst 2-way (free).
// ---------------------------------------------------------------------------
#define P2S 257

__global__ __launch_bounds__(256) void ngp_phase2(
    const float2* __restrict__ ws,
    const unsigned* __restrict__ perm,
    float* __restrict__ out)
{
    __shared__ float2 lds[NLEVELS * P2S];
    __shared__ unsigned nperm[256];
    const unsigned base = blockIdx.x * 256;
    const unsigned t = threadIdx.x;

    nperm[t] = perm[base + t];
    #pragma unroll
    for (int l = 0; l < NLEVELS; ++l)
        lds[l * P2S + t] = ws[(size_t)l * NPTS + base + t];

    __syncthreads();

    #pragma unroll
    for (int it = 0; it < 8; ++it) {
        const unsigned j = it * 256 + t;
        const unsigned pl = j >> 3;          // local sorted point
        const unsigned k = j & 7u;           // level pair
        const float2 a = lds[(2u * k)      * P2S + pl];
        const float2 b = lds[(2u * k + 1u) * P2S + pl];
        v4f v = { a.x, a.y, b.x, b.y };
        *(v4f*)(out + (size_t)nperm[pl] * 32 + k * 4) = v;
    }
}

// ---------------------------------------------------------------------------
// Fallback single-kernel (used only if ws_size is too small).
// ---------------------------------------------------------------------------
__global__ __launch_bounds__(256) void ngp_encode(
    const float* __restrict__ xyz,
    const float* __restrict__ tables,
    float* __restrict__ out,
    LevelParams lp)
{
    const int n = blockIdx.x * 256 + threadIdx.x;
    const float x = xyz[3 * n + 0];
    const float y = xyz[3 * n + 1];
    const float z = xyz[3 * n + 2];

    float acc[2 * NLEVELS];
    const float2* __restrict__ tab_base = (const float2*)tables;

    #pragma unroll
    for (int l = 0; l < NLEVELS; ++l) {
        unsigned h[8];
        float dx, dy, dz;
        ngp_hash(x, y, z, lp.cell[l], h, dx, dy, dz);
        const float2* __restrict__ tab = tab_base + ((size_t)l << 19);
        float2 e[8];
        #pragma unroll
        for (int c = 0; c < 8; ++c) e[c] = tab[h[c]];
        float w[8];
        ngp_weights(dx, dy, dz, w);
        const float2 r = ngp_combine(w, e);
        acc[2 * l + 0] = r.x;
        acc[2 * l + 1] = r.y;
    }

    v4f* o4 = (v4f*)(out + (size_t)n * 32);
    #pragma unroll
    for (int j = 0; j < 8; ++j) {
        v4f v = { acc[4 * j + 0], acc[4 * j + 1],
                  acc[4 * j + 2], acc[4 * j + 3] };
        o4[j] = v;
    }
}

extern "C" void kernel_launch(void* const* d_in, const int* in_sizes, int n_in,
                              void* d_out, int out_size, void* d_ws, size_t ws_size,
                              hipStream_t stream) {
    const float* xyz    = (const float*)d_in[0];
    const float* tables = (const float*)d_in[1];
    float* out          = (float*)d_out;

    // Compute RES exactly as CPython does (glibc double exp/log/pow), then
    // cell = 1/RES in fp32 exactly as numpy float32 division.
    LevelParams lp;
    const double B = std::exp((std::log(2048.0) - std::log(16.0)) / 15.0);
    for (int i = 0; i < NLEVELS; ++i) {
        const double r = std::floor(16.0 * std::pow(B, (double)i));
        lp.cell[i] = 1.0f / (float)r;
    }

    // Workspace layout (16B-aligned blocks):
    //   [0, 64MB)        float2 ws_feat[L][N]
    //   [64MB, +6MB)     float  xyz_sorted[N*3]
    //   [+2MB)           u32    perm[N]
    //   [+128KB)         u32    counts[NBUCKET]
    //   [+128KB)         u32    cursor[NBUCKET]
    const size_t off_feat   = 0;
    const size_t off_xyzs   = off_feat + (size_t)NLEVELS * NPTS * sizeof(float2);
    const size_t off_perm   = off_xyzs + (size_t)NPTS * 3 * sizeof(float);
    const size_t off_counts = off_perm + (size_t)NPTS * sizeof(unsigned);
    const size_t off_cursor = off_counts + (size_t)NBUCKET * sizeof(unsigned);
    const size_t ws_needed  = off_cursor + (size_t)NBUCKET * sizeof(unsigned);

    if (ws_size >= ws_needed) {
        char* wsb = (char*)d_ws;
        float2*   ws_feat    = (float2*)(wsb + off_feat);
        float*    xyz_sorted = (float*)(wsb + off_xyzs);
        unsigned* perm       = (unsigned*)(wsb + off_perm);
        unsigned* counts     = (unsigned*)(wsb + off_counts);
        unsigned* cursor     = (unsigned*)(wsb + off_cursor);

        hipMemsetAsync(counts, 0, NBUCKET * sizeof(unsigned), stream);
        hipLaunchKernelGGL(bucket_count, dim3(NPTS / 256), dim3(256), 0, stream,
                           xyz, counts);
        hipLaunchKernelGGL(bucket_scan, dim3(1), dim3(1024), 0, stream,
                           counts, cursor);
        hipLaunchKernelGGL(bucket_scatter, dim3(NPTS / 256), dim3(256), 0, stream,
                           xyz, cursor, perm, xyz_sorted);
        hipLaunchKernelGGL(ngp_phase1, dim3(NLEVELS * (NPTS / 256)), dim3(256), 0, stream,
                           xyz_sorted, tables, ws_feat, lp);
        hipLaunchKernelGGL(ngp_phase2, dim3(NPTS / 256), dim3(256), 0, stream,
                           ws_feat, perm, out);
    } else {
        hipLaunchKernelGGL(ngp_encode, dim3(NPTS / 256), dim3(256), 0, stream,
                           xyz, tables, out, lp);
    }
}